// Round 1
// baseline (2031.330 us; speedup 1.0000x reference)
//
#include <hip/hip_runtime.h>
#include <math.h>

#define DIM 192
#define HW 1024
#define BATCH 32
#define GRAM_DIM 18528
#define N1 9264
#define N2 4632

// workspace layout (float offsets)
#define OFF_GT    0          // gT[18528][32]
#define OFF_ACC1  592896     // acc1[9264][32]
#define OFF_ACC2  889344     // acc2[4632][32]
#define OFF_H1T   1037568    // h1T[9264][32]
#define OFF_H2T   1334016    // h2T[4632][32]
#define ZERO_CNT  444672     // acc1+acc2 contiguous

__global__ __launch_bounds__(256) void zero_kernel(float* __restrict__ ws) {
    int i = blockIdx.x * 256 + threadIdx.x;
    ws[OFF_ACC1 + i] = 0.f;
}

// Gram: per (tile-pair, sample): 64x64 tile of F F^T, F = x[b] reshaped [192][1024]
__global__ __launch_bounds__(256) void gram_kernel(const float* __restrict__ x,
                                                   float* __restrict__ gT) {
    const int p = blockIdx.x;   // 0..5 tile pair
    const int b = blockIdx.y;   // sample
    int ti, tj;
    if (p == 0)      { ti = 0; tj = 0; }
    else if (p == 1) { ti = 0; tj = 1; }
    else if (p == 2) { ti = 0; tj = 2; }
    else if (p == 3) { ti = 1; tj = 1; }
    else if (p == 4) { ti = 1; tj = 2; }
    else             { ti = 2; tj = 2; }

    __shared__ float Fi[64 * 36];   // stride 36 keeps 16B alignment + kills bank conflicts
    __shared__ float Fj[64 * 36];

    const int t = threadIdx.x;
    const int tx = t & 15, ty = t >> 4;

    float acc[16];
#pragma unroll
    for (int i = 0; i < 16; i++) acc[i] = 0.f;

    const float* xb = x + (size_t)b * DIM * HW;
    const float* xi = xb + (size_t)ti * 64 * HW;
    const float* xj = xb + (size_t)tj * 64 * HW;

    for (int k0 = 0; k0 < HW; k0 += 32) {
        __syncthreads();
        // stage 64 rows x 32 floats for each operand: 512 float4 / 256 threads
#pragma unroll
        for (int s = 0; s < 2; s++) {
            int f = t + s * 256;
            int row = f >> 3;
            int c4 = (f & 7) * 4;
            float4 vi = *(const float4*)(xi + (size_t)row * HW + k0 + c4);
            float4 vj = *(const float4*)(xj + (size_t)row * HW + k0 + c4);
            *(float4*)(&Fi[row * 36 + c4]) = vi;
            *(float4*)(&Fj[row * 36 + c4]) = vj;
        }
        __syncthreads();
#pragma unroll
        for (int kk = 0; kk < 32; kk += 4) {
            float4 av[4], bv[4];
#pragma unroll
            for (int ii = 0; ii < 4; ii++) av[ii] = *(const float4*)(&Fi[(4 * ty + ii) * 36 + kk]);
#pragma unroll
            for (int jj = 0; jj < 4; jj++) bv[jj] = *(const float4*)(&Fj[(4 * tx + jj) * 36 + kk]);
#pragma unroll
            for (int ii = 0; ii < 4; ii++)
#pragma unroll
                for (int jj = 0; jj < 4; jj++)
                    acc[ii * 4 + jj] += av[ii].x * bv[jj].x + av[ii].y * bv[jj].y +
                                        av[ii].z * bv[jj].z + av[ii].w * bv[jj].w;
        }
    }

    // scatter upper-tri (row-major triu order), transposed store gT[idx][b]
#pragma unroll
    for (int ii = 0; ii < 4; ii++) {
        int i = ti * 64 + 4 * ty + ii;
#pragma unroll
        for (int jj = 0; jj < 4; jj++) {
            int j = tj * 64 + 4 * tx + jj;
            if (j >= i) {
                int idx = i * DIM - (i * (i - 1)) / 2 + (j - i);
                gT[(size_t)idx * BATCH + b] = acc[ii * 4 + jj];
            }
        }
    }
}

// C[j][b] += sum_k W[j][k] * AT[k][b]; one neuron per lane, 32 batch accs,
// k split 4-way in-block (wave-uniform) x grid.y chunks; atomic accumulate.
__global__ __launch_bounds__(256) void gemm_kernel(const float* __restrict__ AT,
                                                   const float* __restrict__ W,
                                                   float* __restrict__ acc_out,
                                                   int N, int K, int L) {
    const int t = threadIdx.x;
    const int j = blockIdx.x * 64 + (t & 63);
    const int ksub = __builtin_amdgcn_readfirstlane(t >> 6);
    if (j >= N) return;
    const int kstart = (blockIdx.y * 4 + ksub) * L;

    const float* wp = W + (size_t)j * K + kstart;
    const float* ap = AT + (size_t)kstart * BATCH;

    float acc[32];
#pragma unroll
    for (int b = 0; b < 32; b++) acc[b] = 0.f;

    for (int k = 0; k < L; k += 4) {
        float4 w = *(const float4*)(wp + k);
        const float* a = ap + (size_t)k * BATCH;
#pragma unroll
        for (int kk = 0; kk < 4; kk++) {
            float wv = (kk == 0) ? w.x : (kk == 1) ? w.y : (kk == 2) ? w.z : w.w;
            const float* ar = a + kk * BATCH;
#pragma unroll
            for (int bb = 0; bb < 32; bb += 4) {
                float4 av = *(const float4*)(ar + bb);
                acc[bb]     += wv * av.x;
                acc[bb + 1] += wv * av.y;
                acc[bb + 2] += wv * av.z;
                acc[bb + 3] += wv * av.w;
            }
        }
    }

    float* outp = acc_out + (size_t)j * BATCH;
#pragma unroll
    for (int b = 0; b < 32; b++) atomicAdd(&outp[b], acc[b]);
}

__global__ __launch_bounds__(256) void bias_act_kernel(const float* __restrict__ acc,
                                                       const float* __restrict__ bias,
                                                       float* __restrict__ out, int N) {
    int idx = blockIdx.x * 256 + threadIdx.x;
    int n = idx >> 5;
    float v = acc[idx] + bias[n];
    out[idx] = (v > 0.f) ? v : 0.01f * v;
}

// L3 (64 neurons) + bias + leaky + l2norm + L4 + sigmoid; one block per sample
__global__ __launch_bounds__(256) void final_kernel(const float* __restrict__ h2T,
                                                    const float* __restrict__ W3,
                                                    const float* __restrict__ b3,
                                                    const float* __restrict__ W4,
                                                    const float* __restrict__ b4,
                                                    float* __restrict__ out) {
    const int b = blockIdx.x;
    const int t = threadIdx.x;
    const int n = t & 63;
    const int s = t >> 6;
    const int L = N2 / 4;  // 1158

    const float* wp = W3 + (size_t)n * N2 + s * L;
    const float* ap = h2T + b + (size_t)(s * L) * BATCH;

    float partial = 0.f;
#pragma unroll 2
    for (int k = 0; k < L; k++) partial += wp[k] * ap[(size_t)k * BATCH];

    __shared__ float red[256];
    red[t] = partial;
    __syncthreads();
    if (t < 64) {
        float v = red[t] + red[t + 64] + red[t + 128] + red[t + 192] + b3[n];
        v = (v > 0.f) ? v : 0.01f * v;
        float sq = v * v;
#pragma unroll
        for (int off = 32; off >= 1; off >>= 1) sq += __shfl_xor(sq, off, 64);
        float norm = sqrtf(sq);
        float hn = v / fmaxf(norm, 1e-12f);
        float z = hn * W4[n];
#pragma unroll
        for (int off = 32; off >= 1; off >>= 1) z += __shfl_xor(z, off, 64);
        if (t == 0) out[b] = 1.f / (1.f + expf(-(z + b4[0])));
    }
}

extern "C" void kernel_launch(void* const* d_in, const int* in_sizes, int n_in,
                              void* d_out, int out_size, void* d_ws, size_t ws_size,
                              hipStream_t stream) {
    const float* x  = (const float*)d_in[0];
    const float* W1 = (const float*)d_in[1];
    const float* b1 = (const float*)d_in[2];
    const float* W2 = (const float*)d_in[3];
    const float* b2 = (const float*)d_in[4];
    const float* W3 = (const float*)d_in[5];
    const float* b3 = (const float*)d_in[6];
    const float* W4 = (const float*)d_in[7];
    const float* b4 = (const float*)d_in[8];
    float* out = (float*)d_out;
    float* ws  = (float*)d_ws;

    float* gT   = ws + OFF_GT;
    float* acc1 = ws + OFF_ACC1;
    float* acc2 = ws + OFF_ACC2;
    float* h1T  = ws + OFF_H1T;
    float* h2T  = ws + OFF_H2T;

    hipLaunchKernelGGL(zero_kernel, dim3(ZERO_CNT / 256), dim3(256), 0, stream, ws);
    hipLaunchKernelGGL(gram_kernel, dim3(6, 32), dim3(256), 0, stream, x, gT);
    // L1: K=18528 = (2 grid * 4 waves) * 2316
    hipLaunchKernelGGL(gemm_kernel, dim3(145, 2), dim3(256), 0, stream,
                       gT, W1, acc1, N1, GRAM_DIM, 2316);
    hipLaunchKernelGGL(bias_act_kernel, dim3(N1 * BATCH / 256), dim3(256), 0, stream,
                       acc1, b1, h1T, N1);
    // L2: K=9264 = (3 grid * 4 waves) * 772
    hipLaunchKernelGGL(gemm_kernel, dim3(73, 3), dim3(256), 0, stream,
                       h1T, W2, acc2, N2, N1, 772);
    hipLaunchKernelGGL(bias_act_kernel, dim3(N2 * BATCH / 256), dim3(256), 0, stream,
                       acc2, b2, h2T, N2);
    hipLaunchKernelGGL(final_kernel, dim3(BATCH), dim3(256), 0, stream,
                       h2T, W3, b3, W4, b4, out);
}

// Round 2
// 1113.212 us; speedup vs baseline: 1.8247x; 1.8247x over previous
//
#include <hip/hip_runtime.h>
#include <math.h>

#define DIM 192
#define HW 1024
#define BATCH 32
#define GRAM_DIM 18528
#define N1 9264
#define N2 4632
#define N3 64
#define K1PAD 18528
#define K2PAD 9280   // 9264 padded to 32-multiple
#define K3PAD 4640   // 4632 padded to 32-multiple

// ws float offsets
#define OFF_ACC1 0
#define OFF_ACC2 296448
#define OFF_ACC3 444672
#define ACC_CNT  446720          // acc1+acc2+acc3 contiguous
#define OFF_G    446720          // bf16 [32][18528]
#define OFF_H1   743168          // bf16 [32][9280]
#define OFF_H2   891648          // bf16 [32][4640]

typedef short bf16x8 __attribute__((ext_vector_type(8)));
typedef float f32x4 __attribute__((ext_vector_type(4)));

static __device__ __forceinline__ short f2bf(float f) {
    union { float f; unsigned u; } v; v.f = f;
    unsigned r = (v.u + 0x7fffu + ((v.u >> 16) & 1u)) >> 16;
    return (short)r;
}
static __device__ __forceinline__ bf16x8 cvt8(f32x4 lo, f32x4 hi) {
    bf16x8 r;
    r[0] = f2bf(lo[0]); r[1] = f2bf(lo[1]); r[2] = f2bf(lo[2]); r[3] = f2bf(lo[3]);
    r[4] = f2bf(hi[0]); r[5] = f2bf(hi[1]); r[6] = f2bf(hi[2]); r[7] = f2bf(hi[3]);
    return r;
}

__global__ __launch_bounds__(256) void zero_kernel(float* __restrict__ ws) {
    ws[blockIdx.x * 256 + threadIdx.x] = 0.f;
}

// Gram via MFMA: per (triu 16x16 tile, sample). x fp32 read + inline bf16 cvt.
__global__ __launch_bounds__(256) void gram_mfma(const float* __restrict__ x,
                                                 short* __restrict__ g) {
    const int w = threadIdx.x >> 6, lane = threadIdx.x & 63;
    int t = blockIdx.x * 4 + w;
    if (t >= 78) return;
    const int b = blockIdx.y;
    int ti = 0, rem = t;
    while (rem >= 12 - ti) { rem -= 12 - ti; ti++; }
    const int tj = ti + rem;
    const int m = lane & 15, quad = lane >> 4;
    const float* fa = x + ((size_t)b * DIM + ti * 16 + m) * HW + quad * 8;
    const float* fb = x + ((size_t)b * DIM + tj * 16 + m) * HW + quad * 8;
    f32x4 c = {0.f, 0.f, 0.f, 0.f};
#pragma unroll 4
    for (int s = 0; s < 32; s++) {
        int k = s * 32;
        bf16x8 a  = cvt8(*(const f32x4*)(fa + k), *(const f32x4*)(fa + k + 4));
        bf16x8 bb = cvt8(*(const f32x4*)(fb + k), *(const f32x4*)(fb + k + 4));
        c = __builtin_amdgcn_mfma_f32_16x16x32_bf16(a, bb, c, 0, 0, 0);
    }
    short* grow = g + (size_t)b * GRAM_DIM;
#pragma unroll
    for (int r = 0; r < 4; r++) {
        int i = ti * 16 + quad * 4 + r;
        int j = tj * 16 + m;
        if (j >= i) {
            int idx = i * DIM - (i * (i - 1)) / 2 + (j - i);
            grow[idx] = f2bf(c[r]);
        }
    }
}

// accT[N][32] += W[N][K](fp32, inline bf16 cvt) @ Bm[32][Kpad](bf16)
// wave = 16 W-rows x 32 batch; grid.y = K-split; f32 atomic accumulate.
__global__ __launch_bounds__(256) void gemm_mfma(const float* __restrict__ W,
                                                 const short* __restrict__ Bm,
                                                 float* __restrict__ acc,
                                                 int N, int K, int Kpad,
                                                 int steps, int cs) {
    const int w = threadIdx.x >> 6, lane = threadIdx.x & 63;
    const int tile = blockIdx.x * 4 + w;
    const int j0 = tile * 16;
    if (j0 >= N) return;
    int s0 = blockIdx.y * cs;
    int s1 = min(steps, s0 + cs);
    if (s0 >= s1) return;
    const int m = lane & 15, quad = lane >> 4;
    int row = j0 + m; if (row > N - 1) row = N - 1;   // partial last tile
    const float* wrow  = W + (size_t)row * K;
    const short* brow0 = Bm + (size_t)m * Kpad;
    const short* brow1 = Bm + (size_t)(m + 16) * Kpad;
    f32x4 c0 = {0.f, 0.f, 0.f, 0.f}, c1 = {0.f, 0.f, 0.f, 0.f};
#pragma unroll 2
    for (int s = s0; s < s1; s++) {
        int k = s * 32 + quad * 8;
        int ka = k; if (ka > K - 8) ka = K - 8;  // clamp; B pad is zero there
        bf16x8 a  = cvt8(*(const f32x4*)(wrow + ka), *(const f32x4*)(wrow + ka + 4));
        bf16x8 b0 = *(const bf16x8*)(brow0 + k);
        bf16x8 b1 = *(const bf16x8*)(brow1 + k);
        c0 = __builtin_amdgcn_mfma_f32_16x16x32_bf16(a, b0, c0, 0, 0, 0);
        c1 = __builtin_amdgcn_mfma_f32_16x16x32_bf16(a, b1, c1, 0, 0, 0);
    }
#pragma unroll
    for (int r = 0; r < 4; r++) {
        int j = j0 + quad * 4 + r;
        if (j < N) {
            atomicAdd(&acc[(size_t)j * 32 + m],      c0[r]);
            atomicAdd(&acc[(size_t)j * 32 + 16 + m], c1[r]);
        }
    }
}

// h[b][j] = bf16(leaky(acc[j][b] + bias[j])), zero-fill k-pad
__global__ __launch_bounds__(256) void bias_act(const float* __restrict__ acc,
                                                const float* __restrict__ bias,
                                                short* __restrict__ h,
                                                int N, int Kpad) {
    int j = blockIdx.x * 256 + threadIdx.x;
    int b = blockIdx.y;
    if (j >= Kpad) return;
    short o = 0;
    if (j < N) {
        float v = acc[(size_t)j * 32 + b] + bias[j];
        v = (v > 0.f) ? v : 0.01f * v;
        o = f2bf(v);
    }
    h[(size_t)b * Kpad + j] = o;
}

// bias+leaky+l2norm+L4+sigmoid; one wave per sample
__global__ __launch_bounds__(256) void final_k(const float* __restrict__ acc3,
                                               const float* __restrict__ b3,
                                               const float* __restrict__ W4,
                                               const float* __restrict__ b4,
                                               float* __restrict__ out) {
    int w = threadIdx.x >> 6, n = threadIdx.x & 63;
    int b = blockIdx.x * 4 + w;
    float v = acc3[(size_t)n * 32 + b] + b3[n];
    v = (v > 0.f) ? v : 0.01f * v;
    float sq = v * v;
#pragma unroll
    for (int off = 32; off >= 1; off >>= 1) sq += __shfl_xor(sq, off, 64);
    float hn = v / fmaxf(sqrtf(sq), 1e-12f);
    float z = hn * W4[n];
#pragma unroll
    for (int off = 32; off >= 1; off >>= 1) z += __shfl_xor(z, off, 64);
    if (n == 0) out[b] = 1.f / (1.f + expf(-(z + b4[0])));
}

extern "C" void kernel_launch(void* const* d_in, const int* in_sizes, int n_in,
                              void* d_out, int out_size, void* d_ws, size_t ws_size,
                              hipStream_t stream) {
    const float* x  = (const float*)d_in[0];
    const float* W1 = (const float*)d_in[1];
    const float* b1 = (const float*)d_in[2];
    const float* W2 = (const float*)d_in[3];
    const float* b2 = (const float*)d_in[4];
    const float* W3 = (const float*)d_in[5];
    const float* b3 = (const float*)d_in[6];
    const float* W4 = (const float*)d_in[7];
    const float* b4 = (const float*)d_in[8];
    float* out = (float*)d_out;
    float* ws  = (float*)d_ws;

    float* acc1 = ws + OFF_ACC1;
    float* acc2 = ws + OFF_ACC2;
    float* acc3 = ws + OFF_ACC3;
    short* g  = (short*)(ws + OFF_G);
    short* h1 = (short*)(ws + OFF_H1);
    short* h2 = (short*)(ws + OFF_H2);

    hipLaunchKernelGGL(zero_kernel, dim3(ACC_CNT / 256), dim3(256), 0, stream, ws);
    hipLaunchKernelGGL(gram_mfma, dim3(20, 32), dim3(256), 0, stream, x, g);
    // L1: N=9264 (579 tiles), K=18528 (579 steps), 8-way K-split
    hipLaunchKernelGGL(gemm_mfma, dim3(145, 8), dim3(256), 0, stream,
                       W1, g, acc1, N1, GRAM_DIM, K1PAD, 579, 73);
    hipLaunchKernelGGL(bias_act, dim3(37, 32), dim3(256), 0, stream, acc1, b1, h1, N1, K2PAD);
    // L2: N=4632 (290 tiles), K=9264 (290 steps w/ pad), 8-way K-split
    hipLaunchKernelGGL(gemm_mfma, dim3(73, 8), dim3(256), 0, stream,
                       W2, h1, acc2, N2, N1, K2PAD, 290, 37);
    hipLaunchKernelGGL(bias_act, dim3(19, 32), dim3(256), 0, stream, acc2, b2, h2, N2, K3PAD);
    // L3: N=64 (4 tiles), K=4632 (145 steps w/ pad), 4-way K-split
    hipLaunchKernelGGL(gemm_mfma, dim3(1, 4), dim3(256), 0, stream,
                       W3, h2, acc3, N3, N2, K3PAD, 145, 37);
    hipLaunchKernelGGL(final_k, dim3(8), dim3(256), 0, stream, acc3, b3, W4, b4, out);
}